// Round 4
// baseline (330.960 us; speedup 1.0000x reference)
//
#include <hip/hip_runtime.h>
#include <math.h>

#define DD 64
typedef float v4f __attribute__((ext_vector_type(4)));

// ---------------------------------------------------------------------------
// prep: row_start[v] = lower_bound(dst, v) for v in [0,N], row_start[N]=E.
// Edge-parallel diff-scatter.
// ---------------------------------------------------------------------------
__global__ __launch_bounds__(256) void prep_kernel(const int* __restrict__ dst,
                                                   int* __restrict__ row_start,
                                                   int N, int E) {
    int e = blockIdx.x * blockDim.x + threadIdx.x;
    if (e >= E) return;
    const int b = dst[e];
    const int a = (e == 0) ? -1 : dst[e - 1];
    for (int v = a + 1; v <= b; ++v) row_start[v] = e;
    if (e == E - 1) {
        for (int v = b + 1; v <= N; ++v) row_start[v] = E;
    }
}

// ---------------------------------------------------------------------------
// fused persistent kernel: softmax-aggregate + MLP + residual.
// 2048 blocks x 4 waves grid-stride over nodes (~6 nodes/wave).
//
// Why fusion works THIS time (vs R2's +55us): R2 ran one node per wave, so
// W had no visible reuse and the compiler sank the 16 W loads into a serial
// per-node tail (VGPR=64 proved it). The persistent loop gives W reuse
// across ~6 nodes (the exact property that kept W resident in mlp_kernel),
// plus an opaque asm pin so the loads can't be rematerialized.
//
// Per-node pipeline: row_start for v+2s and the src chunk for v+s are
// issued at the top of node v (src uses e0n/e1n already in registers ->
// no dependent chain), and the residual node_feats load is hoisted.
// Aggregate body is the proven R1/R3 structure: grp=lane>>4 edge slot,
// qd=lane&15 dim quad, all 16B loads, single-pass shift-free softmax
// agg = sum(m*e^m)/sum(e^m), butterfly over lane bits 4,5.
// Epilogue: group 0 writes the 256B agg row to per-wave LDS, lgkmcnt(0)
// (same-wave w->r, no barrier), 16 broadcast ds_read_b128 + 64 FMAs
// against register-resident W, relu + residual, store. Kills the 12.8MB
// agg write + 12.8MB re-read and the third dispatch.
// ---------------------------------------------------------------------------
__global__ __launch_bounds__(256, 3) void fused_kernel(
    const float* __restrict__ node_feats,
    const float* __restrict__ edge_feats,
    const int*   __restrict__ src,
    const int*   __restrict__ row_start,
    const float* __restrict__ W,       // [64,64] row-major: W[j][d]
    const float* __restrict__ bvec,
    float*       __restrict__ out,
    int N)
{
    __shared__ float rowbuf[4][DD];    // one 256B agg row per wave

    const int wave   = threadIdx.x >> 6;
    const int lane   = threadIdx.x & 63;
    const int grp    = lane >> 4;     // edge slot 0..3
    const int qd     = lane & 15;     // dim quad: dims 4qd..4qd+3
    const int stride = gridDim.x * 4;

    // W row for this lane's output dim; pinned resident (reused every node)
    v4f wreg[16];
#pragma unroll
    for (int q = 0; q < 16; ++q) {
        wreg[q] = ((const v4f*)W)[(size_t)lane * 16 + q];   // W[j][4q..4q+3]
        asm volatile("" : "+v"(wreg[q]));   // opaque def: no remat/sinking
    }
    const float bj = bvec[lane];

    int v = blockIdx.x * 4 + wave;
    if (v >= N) return;   // no barriers anywhere -> early out safe

    const v4f* __restrict__ nf4 = (const v4f*)node_feats;
    const v4f* __restrict__ ef4 = (const v4f*)edge_feats;

    // ---- prologue prefetch: current + one node ahead ----
    int e0 = row_start[v];
    int e1 = row_start[v + 1];
    int vn = v + stride;
    int e0n = 0, e1n = 0;
    if (vn < N) { e0n = row_start[vn]; e1n = row_start[vn + 1]; }
    int li0 = e0 + lane;
    int sc  = src[li0 < e1 ? li0 : (e1 > e0 ? e0 : 0)];  // first-chunk src, node v

#define ACCUM(mv, valid)                                \
    {   v4f x;                                          \
        x.x = (valid) ? __expf((mv).x) : 0.f;           \
        x.y = (valid) ? __expf((mv).y) : 0.f;           \
        x.z = (valid) ? __expf((mv).z) : 0.f;           \
        x.w = (valid) ? __expf((mv).w) : 0.f;           \
        se += x;                                        \
        sm += (mv) * x;                                 \
    }

    while (v < N) {
        // ---- issue lookahead loads (consumed one/two nodes later) ----
        int spre_next = 0;
        if (vn < N) {
            const int lin = e0n + lane;
            spre_next = src[lin < e1n ? lin : (e1n > e0n ? e0n : 0)];
        }
        const int v2 = vn + stride;
        int e0nn = 0, e1nn = 0;
        if (v2 < N) { e0nn = row_start[v2]; e1nn = row_start[v2 + 1]; }

        const float res = node_feats[(size_t)v * DD + lane];  // early residual

        // ---- aggregate ----
        v4f se = {0.f, 0.f, 0.f, 0.f};
        v4f sm = {0.f, 0.f, 0.f, 0.f};

        for (int cb = e0; cb < e1; cb += 64) {
            const int li   = cb + lane;
            const int spre = (cb == e0) ? sc
                             : src[li < e1 ? li : e0];   // rare: degree > 64
            const int cend = (cb + 64 < e1) ? (cb + 64) : e1;

            for (int eb = cb; eb < cend; eb += 16) {
                const int rb = eb - cb;                  // 0,16,32,48
                const int sA = __shfl(spre, rb + grp,      64);
                const int sB = __shfl(spre, rb + 4  + grp, 64);
                const int sC = __shfl(spre, rb + 8  + grp, 64);
                const int sD = __shfl(spre, rb + 12 + grp, 64);

                const int eA = eb + grp,      eB = eb + 4 + grp;
                const int eC = eb + 8 + grp,  eD = eb + 12 + grp;
                const bool vA = eA < cend, vB = eB < cend;
                const bool vC = eC < cend, vD = eD < cend;
                const int cA = vA ? eA : e0, cB = vB ? eB : e0;
                const int cC = vC ? eC : e0, cD = vD ? eD : e0;

                const v4f gA = __builtin_nontemporal_load(ef4 + (size_t)cA * 16 + qd);
                const v4f gB = __builtin_nontemporal_load(ef4 + (size_t)cB * 16 + qd);
                const v4f gC = __builtin_nontemporal_load(ef4 + (size_t)cC * 16 + qd);
                const v4f gD = __builtin_nontemporal_load(ef4 + (size_t)cD * 16 + qd);
                const v4f nA = nf4[(size_t)sA * 16 + qd];
                const v4f nB = nf4[(size_t)sB * 16 + qd];
                const v4f nC = nf4[(size_t)sC * 16 + qd];
                const v4f nD = nf4[(size_t)sD * 16 + qd];

                const v4f mA = nA + gA;
                const v4f mB = nB + gB;
                const v4f mC = nC + gC;
                const v4f mD = nD + gD;
                ACCUM(mA, vA);
                ACCUM(mB, vB);
                ACCUM(mC, vC);
                ACCUM(mD, vD);
            }
        }

        // butterfly over the 4 edge slots -> sums replicated in all lanes
        for (int off = 16; off < 64; off <<= 1) {
            se.x += __shfl_xor(se.x, off, 64);
            se.y += __shfl_xor(se.y, off, 64);
            se.z += __shfl_xor(se.z, off, 64);
            se.w += __shfl_xor(se.w, off, 64);
            sm.x += __shfl_xor(sm.x, off, 64);
            sm.y += __shfl_xor(sm.y, off, 64);
            sm.z += __shfl_xor(sm.z, off, 64);
            sm.w += __shfl_xor(sm.w, off, 64);
        }

        v4f a;
        a.x = sm.x / fmaxf(se.x, 1e-38f);   // deg-0 node -> 0
        a.y = sm.y / fmaxf(se.y, 1e-38f);
        a.z = sm.z / fmaxf(se.z, 1e-38f);
        a.w = sm.w / fmaxf(se.w, 1e-38f);

        // ---- fused MLP epilogue ----
        if (grp == 0)
            *(v4f*)(&rowbuf[wave][qd * 4]) = a;
        asm volatile("s_waitcnt lgkmcnt(0)" ::: "memory");  // same-wave w->r

        float acc = bj;
        const v4f* __restrict__ rp = (const v4f*)rowbuf[wave];
#pragma unroll
        for (int q = 0; q < 16; ++q) {
            const v4f av = rp[q];            // broadcast read, conflict-free
            acc = fmaf(av.x, wreg[q].x, acc);
            acc = fmaf(av.y, wreg[q].y, acc);
            acc = fmaf(av.z, wreg[q].z, acc);
            acc = fmaf(av.w, wreg[q].w, acc);
        }
        out[(size_t)v * DD + lane] = fmaxf(acc, 0.f) + res;

        // ---- rotate lookahead state ----
        v  = vn;   vn  = v2;
        e0 = e0n;  e1  = e1n;
        e0n = e0nn; e1n = e1nn;
        sc = spre_next;
    }
#undef ACCUM
}

// ---------------------------------------------------------------------------
extern "C" void kernel_launch(void* const* d_in, const int* in_sizes, int n_in,
                              void* d_out, int out_size, void* d_ws, size_t ws_size,
                              hipStream_t stream) {
    const float* node_feats = (const float*)d_in[0];  // [N, 64]
    const float* edge_feats = (const float*)d_in[1];  // [E, 64]
    const int*   src        = (const int*)  d_in[2];  // [E]
    const int*   dst        = (const int*)  d_in[3];  // [E] sorted
    const float* W          = (const float*)d_in[4];  // [64, 64]
    const float* bvec       = (const float*)d_in[5];  // [64]
    float*       out        = (float*)d_out;

    const int N = in_sizes[0] / DD;
    const int E = in_sizes[2];

    // workspace: row_start only ((N+1) ints)
    int* row_start = (int*)d_ws;

    {
        int blocks = (E + 255) / 256;
        prep_kernel<<<blocks, 256, 0, stream>>>(dst, row_start, N, E);
    }
    {
        int maxb = (N + 3) / 4;
        int blocks = maxb < 2048 ? maxb : 2048;   // persistent waves
        fused_kernel<<<blocks, 256, 0, stream>>>(node_feats, edge_feats, src,
                                                 row_start, W, bvec, out, N);
    }
}

// Round 5
// 318.959 us; speedup vs baseline: 1.0376x; 1.0376x over previous
//
#include <hip/hip_runtime.h>
#include <math.h>

#define DD 64
typedef float v4f __attribute__((ext_vector_type(4)));

// ---------------------------------------------------------------------------
// prep: row_start[v] = lower_bound(dst, v) for v in [0,N], row_start[N]=E.
// Edge-parallel diff-scatter: thread e fills row_start for every v in
// (dst[e-1], dst[e]]  (and [0, dst[0]] for e==0, (dst[E-1], N] for e==E-1).
// Streaming reads, ~N scattered dword writes total.
// ---------------------------------------------------------------------------
__global__ __launch_bounds__(256) void prep_kernel(const int* __restrict__ dst,
                                                   int* __restrict__ row_start,
                                                   int N, int E) {
    int e = blockIdx.x * blockDim.x + threadIdx.x;
    if (e >= E) return;
    const int b = dst[e];
    const int a = (e == 0) ? -1 : dst[e - 1];
    for (int v = a + 1; v <= b; ++v) row_start[v] = e;
    if (e == E - 1) {
        for (int v = b + 1; v <= N; ++v) row_start[v] = E;
    }
}

// ---------------------------------------------------------------------------
// phase 1: one wave per destination node -> agg[v][:] in workspace.
// Lane map: grp = lane>>4 (edge slot), qd = lane&15 (dim quad); all loads are
// 16B float4. 64-edge coalesced src preload distributed to slots via __shfl;
// 16 edges per inner step -> 8 independent 16B loads in flight. Single
// shift-free softmax pass: agg = sum(m*e^m)/sum(e^m).
// Session verdict (R1-R4): this non-persistent form ties/beats persistent
// waves, lookahead, and both fusion attempts. Agg runs at ~3.6 TB/s
// effective on a mixed stream+gather pattern -> near its practical ceiling.
// ---------------------------------------------------------------------------
__global__ __launch_bounds__(256) void agg_kernel(
    const float* __restrict__ node_feats,
    const float* __restrict__ edge_feats,
    const int*   __restrict__ src,
    const int*   __restrict__ row_start,
    float*       __restrict__ agg,
    int N)
{
    const int wave = threadIdx.x >> 6;
    const int lane = threadIdx.x & 63;
    const int grp  = lane >> 4;     // edge slot 0..3
    const int qd   = lane & 15;     // dim quad: dims 4qd..4qd+3
    const int v = blockIdx.x * 4 + wave;
    if (v >= N) return;

    const int e0 = row_start[v];
    const int e1 = row_start[v + 1];

    const v4f* __restrict__ nf4 = (const v4f*)node_feats;
    const v4f* __restrict__ ef4 = (const v4f*)edge_feats;

    v4f se = {0.f, 0.f, 0.f, 0.f};   // sum exp(m), this slot's edges
    v4f sm = {0.f, 0.f, 0.f, 0.f};   // sum m*exp(m)

#define ACCUM(mv, valid)                                \
    {   v4f x;                                          \
        x.x = (valid) ? __expf((mv).x) : 0.f;           \
        x.y = (valid) ? __expf((mv).y) : 0.f;           \
        x.z = (valid) ? __expf((mv).z) : 0.f;           \
        x.w = (valid) ? __expf((mv).w) : 0.f;           \
        se += x;                                        \
        sm += (mv) * x;                                 \
    }

    for (int cb = e0; cb < e1; cb += 64) {
        // coalesced preload of this chunk's src indices: lane -> edge cb+lane
        const int li   = cb + lane;
        const int spre = src[li < e1 ? li : e0];        // clamp keeps it in-bounds
        const int cend = (cb + 64 < e1) ? (cb + 64) : e1;

        for (int eb = cb; eb < cend; eb += 16) {
            const int rb = eb - cb;                     // 0,16,32,48
            // src index for each of the 4 rounds' slot-edges (register path)
            const int sA = __shfl(spre, rb + grp,      64);
            const int sB = __shfl(spre, rb + 4  + grp, 64);
            const int sC = __shfl(spre, rb + 8  + grp, 64);
            const int sD = __shfl(spre, rb + 12 + grp, 64);

            const int eA = eb + grp,      eB = eb + 4 + grp;
            const int eC = eb + 8 + grp,  eD = eb + 12 + grp;
            const bool vA = eA < cend, vB = eB < cend;
            const bool vC = eC < cend, vD = eD < cend;
            const int cA = vA ? eA : e0, cB = vB ? eB : e0;
            const int cC = vC ? eC : e0, cD = vD ? eD : e0;

            // 8 independent 16B loads in flight
            const v4f gA = __builtin_nontemporal_load(ef4 + (size_t)cA * 16 + qd);
            const v4f gB = __builtin_nontemporal_load(ef4 + (size_t)cB * 16 + qd);
            const v4f gC = __builtin_nontemporal_load(ef4 + (size_t)cC * 16 + qd);
            const v4f gD = __builtin_nontemporal_load(ef4 + (size_t)cD * 16 + qd);
            const v4f nA = nf4[(size_t)sA * 16 + qd];
            const v4f nB = nf4[(size_t)sB * 16 + qd];
            const v4f nC = nf4[(size_t)sC * 16 + qd];
            const v4f nD = nf4[(size_t)sD * 16 + qd];

            const v4f mA = nA + gA;
            const v4f mB = nB + gB;
            const v4f mC = nC + gC;
            const v4f mD = nD + gD;
            ACCUM(mA, vA);
            ACCUM(mB, vB);
            ACCUM(mC, vC);
            ACCUM(mD, vD);
        }
    }
#undef ACCUM

    // butterfly over the 4 edge slots (lane bits 4,5)
    for (int off = 16; off < 64; off <<= 1) {
        se.x += __shfl_xor(se.x, off, 64);
        se.y += __shfl_xor(se.y, off, 64);
        se.z += __shfl_xor(se.z, off, 64);
        se.w += __shfl_xor(se.w, off, 64);
        sm.x += __shfl_xor(sm.x, off, 64);
        sm.y += __shfl_xor(sm.y, off, 64);
        sm.z += __shfl_xor(sm.z, off, 64);
        sm.w += __shfl_xor(sm.w, off, 64);
    }

    if (grp == 0) {
        v4f a;
        a.x = sm.x / fmaxf(se.x, 1e-38f);   // deg-0 node -> 0
        a.y = sm.y / fmaxf(se.y, 1e-38f);
        a.z = sm.z / fmaxf(se.z, 1e-38f);
        a.w = sm.w / fmaxf(se.w, 1e-38f);
        ((v4f*)agg)[(size_t)v * 16 + qd] = a;   // 16 lanes x 16B = 256B row
    }
}

// ---------------------------------------------------------------------------
// phase 2: out = relu(agg @ W^T + b) + node_feats.
// lane = output dim j; W row j (contiguous 256B) lives in 16 v4f registers —
// kept resident by the compiler because of reuse across the 8-node loop
// (the R2/R4 fusion attempts proved single-use W gets sunk into a serial
// per-node tail). Per node: wave-uniform agg row read (scalar/broadcast
// path), 64 register FMAs, coalesced residual load + store.
// ---------------------------------------------------------------------------
__global__ __launch_bounds__(256) void mlp_kernel(
    const float* __restrict__ agg,
    const float* __restrict__ node_feats,
    const float* __restrict__ W,       // [64,64] row-major: W[j][d]
    const float* __restrict__ bvec,
    float*       __restrict__ out,
    int N)
{
    const int lane = threadIdx.x & 63;   // output dim j
    const int wave = threadIdx.x >> 6;

    v4f wreg[16];
#pragma unroll
    for (int q = 0; q < 16; ++q)
        wreg[q] = ((const v4f*)W)[(size_t)lane * 16 + q];   // W[j][4q..4q+3]
    const float bj = bvec[lane];

    const int v0    = blockIdx.x * 32 + wave * 8;
    const int v_end = (v0 + 8 < N) ? (v0 + 8) : N;

    for (int v = v0; v < v_end; ++v) {
        const int vu = __builtin_amdgcn_readfirstlane(v);
        const v4f* __restrict__ arow = (const v4f*)(agg + (size_t)vu * DD);
        float acc = bj;
#pragma unroll
        for (int q = 0; q < 16; ++q) {
            const v4f a = arow[q];       // wave-uniform address
            acc = fmaf(a.x, wreg[q].x, acc);
            acc = fmaf(a.y, wreg[q].y, acc);
            acc = fmaf(a.z, wreg[q].z, acc);
            acc = fmaf(a.w, wreg[q].w, acc);
        }
        const float res = node_feats[(size_t)vu * DD + lane];
        out[(size_t)vu * DD + lane] = fmaxf(acc, 0.f) + res;
    }
}

// ---------------------------------------------------------------------------
extern "C" void kernel_launch(void* const* d_in, const int* in_sizes, int n_in,
                              void* d_out, int out_size, void* d_ws, size_t ws_size,
                              hipStream_t stream) {
    const float* node_feats = (const float*)d_in[0];  // [N, 64]
    const float* edge_feats = (const float*)d_in[1];  // [E, 64]
    const int*   src        = (const int*)  d_in[2];  // [E]
    const int*   dst        = (const int*)  d_in[3];  // [E] sorted
    const float* W          = (const float*)d_in[4];  // [64, 64]
    const float* bvec       = (const float*)d_in[5];  // [64]
    float*       out        = (float*)d_out;

    const int N = in_sizes[0] / DD;
    const int E = in_sizes[2];

    // workspace: row_start[(N+1) ints] | pad to 256B | agg[N*64 floats]
    int*   row_start = (int*)d_ws;
    size_t agg_off = (((size_t)(N + 1) * sizeof(int)) + 255) & ~(size_t)255;
    float* agg = (float*)((char*)d_ws + agg_off);

    {
        int blocks = (E + 255) / 256;
        prep_kernel<<<blocks, 256, 0, stream>>>(dst, row_start, N, E);
    }
    {
        int blocks = (N + 3) / 4;  // 4 waves (nodes) per 256-thread block
        agg_kernel<<<blocks, 256, 0, stream>>>(node_feats, edge_feats, src,
                                               row_start, agg, N);
    }
    {
        int blocks = (N + 31) / 32;  // 32 nodes per block (8 per wave)
        mlp_kernel<<<blocks, 256, 0, stream>>>(agg, node_feats, W, bvec, out, N);
    }
}